// Round 8
// baseline (239.579 us; speedup 1.0000x reference)
//
#include <hip/hip_runtime.h>

#define NBINS 256
#define BLOCK 64                     // one wave per block
#define CNT_DW (64 * 64)             // dword (bin>>2)*64 + lane  -> bank = lane&31 (2-way, free)
#define BIN_SCALE (256.0f / 255.0f)  // torch.histc width=(255-0)/256; idx=floor(x/width)
#define CAP_F4 62                    // <=62 full float4 + 1 tail f4 + 1 scalar < 255 per byte counter

__global__ void zero_out(float* __restrict__ out) {
    const int i = blockIdx.x * blockDim.x + threadIdx.x;
    if (i < 2 * NBINS) out[i] = 0.0f;
}

// element -> (lane-private counter dword, packed byte increment); OOR -> inc=0 into slot t
__device__ __forceinline__ void classify(float v, int t, int& dw, unsigned& inc) {
    int idx = (int)(v * BIN_SCALE);          // trunc == floor for v>=0 (cvt saturates otherwise)
    idx = idx < 255 ? idx : 255;             // x==255 -> last bin
    const bool ok = (v >= 0.0f) && (v <= 255.0f);
    dw = ok ? (((((unsigned)idx) >> 2) << 6) + t) : t;   // OOR: slot t, inc 0 (harmless)
    inc = ok ? (1u << ((idx & 3) << 3)) : 0u;
}

__global__ __launch_bounds__(BLOCK) void hist_kernel(const float* __restrict__ x,
                                                     unsigned int* __restrict__ partial,
                                                     float* __restrict__ out,
                                                     int n, int G, int use_ws) {
    __shared__ unsigned int cnt[CNT_DW];     // 16 KB: per-lane byte counters, bank-aligned
    const int t = threadIdx.x;               // == lane (1 wave/block)

    {
        uint4* z4 = (uint4*)cnt;
#pragma unroll
        for (int i = 0; i < CNT_DW / 4 / BLOCK; ++i)
            z4[t + i * BLOCK] = make_uint4(0u, 0u, 0u, 0u);
    }
    __syncthreads();

    const int n4 = n >> 2;
    const float4* __restrict__ x4 = (const float4*)x;
    const int S = G * BLOCK;
    const int i0 = blockIdx.x * BLOCK + t;
    const int K = n4 / S;                    // uniform full iterations for ALL threads

    if (K > 0) {
        // 4-deep global prefetch ring (registers; loop unrolled by 4 below)
        float4 ring[4];
#pragma unroll
        for (int d = 0; d < 4; ++d)
            ring[d] = (d < K) ? x4[i0 + d * S] : make_float4(-1.f, -1.f, -1.f, -1.f);

        // ---- peeled k = 0: classify + issue reads (no merge yet) ----
        float4 v = ring[0];
        if (4 < K) ring[0] = x4[i0 + 4 * S];
        int pd0, pd1, pd2, pd3; unsigned ps0, ps1, ps2, ps3;
        classify(v.x, t, pd0, ps0);
        classify(v.y, t, pd1, ps1);
        classify(v.z, t, pd2, ps2);
        classify(v.w, t, pd3, ps3);
        unsigned po0 = cnt[pd0], po1 = cnt[pd1], po2 = cnt[pd2], po3 = cnt[pd3];

        // ---- 1-stage DS pipeline: merge/write k-1, then read k ----
#pragma unroll 4
        for (int k = 1; k < K; ++k) {
            v = ring[k & 3];
            if (k + 4 < K) ring[k & 3] = x4[i0 + (k + 4) * S];

            int d0, d1, d2, d3; unsigned s0, s1, s2, s3;
            classify(v.x, t, d0, s0);
            classify(v.y, t, d1, s1);
            classify(v.z, t, d2, s2);
            classify(v.w, t, d3, s3);

            // merge k-1 (lgkm wait for po* lands here, hidden behind classify)
            unsigned w0 = po0 + ps0;
            unsigned w1 = po1 + ps1 + (pd1 == pd0 ? ps0 : 0u);
            unsigned w2 = po2 + ps2 + (pd2 == pd0 ? ps0 : 0u) + (pd2 == pd1 ? ps1 : 0u);
            unsigned w3 = po3 + ps3 + (pd3 == pd0 ? ps0 : 0u) + (pd3 == pd1 ? ps1 : 0u)
                                    + (pd3 == pd2 ? ps2 : 0u);
            cnt[pd0] = w0; cnt[pd1] = w1; cnt[pd2] = w2; cnt[pd3] = w3;

            // issue k's reads AFTER k-1's writes (DS in-order per wave -> RAW safe)
            po0 = cnt[d0]; po1 = cnt[d1]; po2 = cnt[d2]; po3 = cnt[d3];
            pd0 = d0; pd1 = d1; pd2 = d2; pd3 = d3;
            ps0 = s0; ps1 = s1; ps2 = s2; ps3 = s3;
        }
        // ---- drain ----
        unsigned w0 = po0 + ps0;
        unsigned w1 = po1 + ps1 + (pd1 == pd0 ? ps0 : 0u);
        unsigned w2 = po2 + ps2 + (pd2 == pd0 ? ps0 : 0u) + (pd2 == pd1 ? ps1 : 0u);
        unsigned w3 = po3 + ps3 + (pd3 == pd0 ? ps0 : 0u) + (pd3 == pd1 ? ps1 : 0u)
                                + (pd3 == pd2 ? ps2 : 0u);
        cnt[pd0] = w0; cnt[pd1] = w1; cnt[pd2] = w2; cnt[pd3] = w3;
    }

    // tail float4 (threads with one extra f4; sequential RMW, same-lane in-order)
    {
        const int it = i0 + K * S;
        if (it < n4) {
            float4 v = x4[it];
            int d; unsigned s;
            classify(v.x, t, d, s); cnt[d] += s;
            classify(v.y, t, d, s); cnt[d] += s;
            classify(v.z, t, d, s); cnt[d] += s;
            classify(v.w, t, d, s); cnt[d] += s;
        }
    }
    // scalar remainder (n % 4 elements)
    for (int j = (n4 << 2) + i0; j < n; j += S) {
        int d; unsigned s;
        classify(x[j], t, d, s);
        cnt[d] += s;
    }
    __syncthreads();

    // Epilogue: lane L sums bin-quad L over all 64 lane slices.
    // Rotated reads: addr L*64 + ((L+k)&63) -> banks distinct mod 32 (free).
    unsigned accA = 0, accB = 0;   // packed u16 pairs: bytes{0,2} / bytes{1,3}
#pragma unroll 16
    for (int k = 0; k < 64; ++k) {
        unsigned u = cnt[(t << 6) + ((t + k) & 63)];
        accA += u & 0x00FF00FFu;
        accB += (u >> 8) & 0x00FF00FFu;
    }
    const unsigned b0 = accA & 0xFFFFu, b2 = accA >> 16;
    const unsigned b1 = accB & 0xFFFFu, b3 = accB >> 16;

    if (use_ws) {
        ((uint4*)(partial + (size_t)blockIdx.x * NBINS))[t] = make_uint4(b0, b1, b2, b3);
    } else {
        if (b0) atomicAdd(&out[4 * t + 0], (float)b0);
        if (b1) atomicAdd(&out[4 * t + 1], (float)b1);
        if (b2) atomicAdd(&out[4 * t + 2], (float)b2);
        if (b3) atomicAdd(&out[4 * t + 3], (float)b3);
    }
}

// 256 blocks; block j sums a g-slice (coalesced 1 KB reads), <=256 atomics/bin total.
__global__ __launch_bounds__(NBINS) void reduce_kernel(const unsigned int* __restrict__ partial,
                                                       float* __restrict__ out,
                                                       int G, int slice) {
    const int bin = threadIdx.x;
    const int g0 = blockIdx.x * slice;
    const int g1 = (g0 + slice < G) ? (g0 + slice) : G;
    unsigned s = 0;
    for (int g = g0; g < g1; ++g)
        s += partial[(size_t)g * NBINS + bin];
    if (s) atomicAdd(&out[bin], (float)s);   // exact: integers < 2^24
}

__global__ void count_kernel(const void* __restrict__ bs_raw,
                             float* __restrict__ out) {
    const int as_int = *(const int*)bs_raw;
    float bs;
    if (as_int >= 1 && as_int < (1 << 20)) {
        bs = (float)as_int;
    } else {
        bs = *(const float*)bs_raw;
    }
    out[NBINS + threadIdx.x] = bs * out[0];
}

extern "C" void kernel_launch(void* const* d_in, const int* in_sizes, int n_in,
                              void* d_out, int out_size, void* d_ws, size_t ws_size,
                              hipStream_t stream) {
    const void* bs_ptr;
    const float* x;
    int n;
    if (n_in >= 2 && in_sizes[0] == 1) {
        bs_ptr = d_in[0];
        x = (const float*)d_in[1];
        n = in_sizes[1];
    } else {
        bs_ptr = d_in[1];
        x = (const float*)d_in[0];
        n = in_sizes[0];
    }

    float* out = (float*)d_out;                    // [256 hist | 256 count], float32
    unsigned int* partial = (unsigned int*)d_ws;   // [G][256] u32 partials

    const long n4 = (long)n >> 2;
    int G = (int)((n4 + (long)BLOCK * CAP_F4 - 1) / ((long)BLOCK * CAP_F4));
    if (G < 1) G = 1;

    const size_t ws_need = (size_t)G * NBINS * sizeof(unsigned int);
    const int use_ws = (ws_size >= ws_need) ? 1 : 0;

    zero_out<<<2, 256, 0, stream>>>(out);
    hist_kernel<<<G, BLOCK, 0, stream>>>(x, partial, out, n, G, use_ws);
    if (use_ws) {
        const int slice = (G + NBINS - 1) / NBINS;
        reduce_kernel<<<NBINS, NBINS, 0, stream>>>(partial, out, G, slice);
    }
    count_kernel<<<1, NBINS, 0, stream>>>(bs_ptr, out);
}

// Round 9
// 223.614 us; speedup vs baseline: 1.0714x; 1.0714x over previous
//
#include <hip/hip_runtime.h>

#define NBINS 256
#define BLOCK 64                     // one wave per block
#define CNT_DW (64 * 64)             // dword (bin>>2)*64 + lane -> bank = lane&31 (2-way, free)
#define BIN_SCALE (256.0f / 255.0f)  // torch.histc width=(255-0)/256; idx=floor(x/width)
#define TARGET_G 2560                // 10 blocks/CU (LDS cap: 160KB / 16KB)
#define MAX_K 61                     // byte-counter overflow guard: 61*4+8 < 255

__global__ void zero_out(float* __restrict__ out) {
    const int i = blockIdx.x * blockDim.x + threadIdx.x;
    if (i < 2 * NBINS) out[i] = 0.0f;
}

// element -> (lane-private counter dword, packed byte increment); OOR -> inc=0
__device__ __forceinline__ void classify(float v, int t, int& dw, unsigned& inc) {
    int idx = (int)(v * BIN_SCALE);          // trunc == floor for v>=0
    idx = idx < 255 ? idx : 255;             // x==255 -> last bin
    const bool ok = (v >= 0.0f) && (v <= 255.0f);
    dw = ok ? (((((unsigned)idx) >> 2) << 6) + t) : t;
    inc = ok ? (1u << ((idx & 3) << 3)) : 0u;
}

__global__ __launch_bounds__(BLOCK) void hist_kernel(const float* __restrict__ x,
                                                     unsigned int* __restrict__ partial,
                                                     float* __restrict__ out,
                                                     int n, int G, int use_ws) {
    __shared__ unsigned int cnt[CNT_DW];     // 16 KB lane-private byte counters
    const int t = threadIdx.x;               // == lane

    {
        uint4* z4 = (uint4*)cnt;
#pragma unroll
        for (int i = 0; i < CNT_DW / 4 / BLOCK; ++i)
            z4[t + i * BLOCK] = make_uint4(0u, 0u, 0u, 0u);
    }
    __syncthreads();

    const int n4 = n >> 2;
    const float4* __restrict__ x4 = (const float4*)x;
    const int S = G * BLOCK;
    const int i0 = blockIdx.x * BLOCK + t;
    const int K = n4 / S;                    // uniform iterations for all threads

    if (K > 0) {
        // NAMED registers only — no arrays, no scratch.
        float4 v = x4[i0];                           // elem 0
        float4 nxt = (K > 1) ? x4[i0 + S] : v;       // elem 1 (init-time branch only)

        int pd0, pd1, pd2, pd3; unsigned ps0, ps1, ps2, ps3;
        classify(v.x, t, pd0, ps0);
        classify(v.y, t, pd1, ps1);
        classify(v.z, t, pd2, ps2);
        classify(v.w, t, pd3, ps3);
        unsigned po0 = cnt[pd0], po1 = cnt[pd1], po2 = cnt[pd2], po3 = cnt[pd3];

        for (int k = 1; k < K; ++k) {
            v = nxt;                                 // elem k
            // prefetch elem k+1; last iter re-loads i0 (value discarded)
            const int pa = (k + 1 < K) ? (i0 + (k + 1) * S) : i0;
            nxt = x4[pa];

            int d0, d1, d2, d3; unsigned s0, s1, s2, s3;
            classify(v.x, t, d0, s0);
            classify(v.y, t, d1, s1);
            classify(v.z, t, d2, s2);
            classify(v.w, t, d3, s3);

            // merge + write iter k-1 (lgkm wait lands here, behind classify)
            unsigned w0 = po0 + ps0;
            unsigned w1 = po1 + ps1 + (pd1 == pd0 ? ps0 : 0u);
            unsigned w2 = po2 + ps2 + (pd2 == pd0 ? ps0 : 0u) + (pd2 == pd1 ? ps1 : 0u);
            unsigned w3 = po3 + ps3 + (pd3 == pd0 ? ps0 : 0u) + (pd3 == pd1 ? ps1 : 0u)
                                    + (pd3 == pd2 ? ps2 : 0u);
            cnt[pd0] = w0; cnt[pd1] = w1; cnt[pd2] = w2; cnt[pd3] = w3;

            // issue iter k's reads AFTER k-1's writes (DS in-order per wave -> RAW safe)
            po0 = cnt[d0]; po1 = cnt[d1]; po2 = cnt[d2]; po3 = cnt[d3];
            pd0 = d0; pd1 = d1; pd2 = d2; pd3 = d3;
            ps0 = s0; ps1 = s1; ps2 = s2; ps3 = s3;
        }
        // drain
        unsigned w0 = po0 + ps0;
        unsigned w1 = po1 + ps1 + (pd1 == pd0 ? ps0 : 0u);
        unsigned w2 = po2 + ps2 + (pd2 == pd0 ? ps0 : 0u) + (pd2 == pd1 ? ps1 : 0u);
        unsigned w3 = po3 + ps3 + (pd3 == pd0 ? ps0 : 0u) + (pd3 == pd1 ? ps1 : 0u)
                                + (pd3 == pd2 ? ps2 : 0u);
        cnt[pd0] = w0; cnt[pd1] = w1; cnt[pd2] = w2; cnt[pd3] = w3;
    }

    // tail float4 (threads with one extra f4; sequential same-lane RMW)
    {
        const int it = i0 + K * S;
        if (it < n4) {
            float4 v = x4[it];
            int d; unsigned s;
            classify(v.x, t, d, s); cnt[d] += s;
            classify(v.y, t, d, s); cnt[d] += s;
            classify(v.z, t, d, s); cnt[d] += s;
            classify(v.w, t, d, s); cnt[d] += s;
        }
    }
    // scalar remainder (n % 4)
    for (int j = (n4 << 2) + i0; j < n; j += S) {
        int d; unsigned s;
        classify(x[j], t, d, s);
        cnt[d] += s;
    }
    __syncthreads();

    // Epilogue: lane L sums bin-quad L over all 64 lane slices.
    // Rotated reads: addr L*64 + ((L+k)&63) -> 2 lanes/bank (free).
    unsigned accA = 0, accB = 0;   // packed u16 pairs: bytes{0,2} / bytes{1,3}
#pragma unroll 16
    for (int k = 0; k < 64; ++k) {
        unsigned u = cnt[(t << 6) + ((t + k) & 63)];
        accA += u & 0x00FF00FFu;
        accB += (u >> 8) & 0x00FF00FFu;
    }
    const unsigned b0 = accA & 0xFFFFu, b2 = accA >> 16;
    const unsigned b1 = accB & 0xFFFFu, b3 = accB >> 16;

    if (use_ws) {
        ((uint4*)(partial + (size_t)blockIdx.x * NBINS))[t] = make_uint4(b0, b1, b2, b3);
    } else {
        if (b0) atomicAdd(&out[4 * t + 0], (float)b0);
        if (b1) atomicAdd(&out[4 * t + 1], (float)b1);
        if (b2) atomicAdd(&out[4 * t + 2], (float)b2);
        if (b3) atomicAdd(&out[4 * t + 3], (float)b3);
    }
}

// 256 blocks; block j sums a g-slice (coalesced 1 KB reads), <=256 atomics/bin total.
__global__ __launch_bounds__(NBINS) void reduce_kernel(const unsigned int* __restrict__ partial,
                                                       float* __restrict__ out,
                                                       int G, int slice) {
    const int bin = threadIdx.x;
    const int g0 = blockIdx.x * slice;
    const int g1 = (g0 + slice < G) ? (g0 + slice) : G;
    unsigned s = 0;
    for (int g = g0; g < g1; ++g)
        s += partial[(size_t)g * NBINS + bin];
    if (s) atomicAdd(&out[bin], (float)s);   // exact: integers < 2^24
}

__global__ void count_kernel(const void* __restrict__ bs_raw,
                             float* __restrict__ out) {
    const int as_int = *(const int*)bs_raw;
    float bs;
    if (as_int >= 1 && as_int < (1 << 20)) {
        bs = (float)as_int;
    } else {
        bs = *(const float*)bs_raw;
    }
    out[NBINS + threadIdx.x] = bs * out[0];
}

extern "C" void kernel_launch(void* const* d_in, const int* in_sizes, int n_in,
                              void* d_out, int out_size, void* d_ws, size_t ws_size,
                              hipStream_t stream) {
    const void* bs_ptr;
    const float* x;
    int n;
    if (n_in >= 2 && in_sizes[0] == 1) {
        bs_ptr = d_in[0];
        x = (const float*)d_in[1];
        n = in_sizes[1];
    } else {
        bs_ptr = d_in[1];
        x = (const float*)d_in[0];
        n = in_sizes[0];
    }

    float* out = (float*)d_out;                    // [256 hist | 256 count], float32
    unsigned int* partial = (unsigned int*)d_ws;   // [G][256] u32 partials

    const long n4 = (long)n >> 2;
    // G: at least TARGET_G for occupancy, more if needed for byte-counter safety
    long Gmin = (n4 + (long)BLOCK * MAX_K - 1) / ((long)BLOCK * MAX_K);
    int G = (int)(Gmin > TARGET_G ? Gmin : TARGET_G);
    if (G < 1) G = 1;

    const size_t ws_need = (size_t)G * NBINS * sizeof(unsigned int);
    const int use_ws = (ws_size >= ws_need) ? 1 : 0;

    zero_out<<<2, 256, 0, stream>>>(out);
    hist_kernel<<<G, BLOCK, 0, stream>>>(x, partial, out, n, G, use_ws);
    if (use_ws) {
        const int slice = (G + NBINS - 1) / NBINS;
        reduce_kernel<<<NBINS, NBINS, 0, stream>>>(partial, out, G, slice);
    }
    count_kernel<<<1, NBINS, 0, stream>>>(bs_ptr, out);
}

// Round 10
// 204.618 us; speedup vs baseline: 1.1709x; 1.0928x over previous
//
#include <hip/hip_runtime.h>

#define NBINS 256
#define BLOCK 256                     // 4 waves/block
#define CNT_DW (64 * BLOCK)           // dword (bin>>2)*256 + tid -> bank = tid&31 (2-way, free)
#define BIN_SCALE (256.0f / 255.0f)   // torch.histc width=(255-0)/256; idx=floor(x/width)
#define TARGET_G 1024                 // 2 blocks/CU resident (64KB LDS), 2 generations
#define MAX_PER_THREAD 240            // byte-counter overflow guard

__global__ void zero_out(float* __restrict__ out) {
    const int i = blockIdx.x * blockDim.x + threadIdx.x;
    if (i < 2 * NBINS) out[i] = 0.0f;
}

// element -> (thread-private counter dword, packed byte increment); OOR -> inc=0
__device__ __forceinline__ void classify(float v, int t, int& dw, unsigned& inc) {
    int idx = (int)(v * BIN_SCALE);          // trunc == floor for v>=0
    idx = idx < 255 ? idx : 255;             // x==255 -> last bin
    const bool ok = (v >= 0.0f) && (v <= 255.0f);
    dw = ok ? ((((unsigned)idx >> 2) << 8) + t) : t;
    inc = ok ? (1u << ((idx & 3) << 3)) : 0u;
}

__global__ __launch_bounds__(BLOCK) void hist_kernel(const float* __restrict__ x,
                                                     unsigned int* __restrict__ partial,
                                                     float* __restrict__ out,
                                                     int n, int G, int use_ws) {
    __shared__ unsigned int cnt[CNT_DW];     // 64 KB: thread-private byte counters
    const int t = threadIdx.x;

    {
        uint4* z4 = (uint4*)cnt;
#pragma unroll
        for (int i = 0; i < CNT_DW / 4 / BLOCK; ++i)
            z4[t + i * BLOCK] = make_uint4(0u, 0u, 0u, 0u);
    }
    __syncthreads();

    const int n4 = n >> 2;
    const float4* __restrict__ x4 = (const float4*)x;
    const int S = G * BLOCK;
    const int i0 = blockIdx.x * BLOCK + t;
    const int K = (i0 < n4) ? ((n4 - i0 + S - 1) / S) : 0;  // my f4 count (grid-stride)

    // DS pipeline state: previous group's (dword, inc, old-value)
    int pd0 = t, pd1 = t, pd2 = t, pd3 = t;
    unsigned ps0 = 0, ps1 = 0, ps2 = 0, ps3 = 0;
    unsigned po0 = 0, po1 = 0, po2 = 0, po3 = 0;
    bool have_p = false;

    auto process = [&](const float4& v) {
        int d0, d1, d2, d3; unsigned s0, s1, s2, s3;
        classify(v.x, t, d0, s0);
        classify(v.y, t, d1, s1);
        classify(v.z, t, d2, s2);
        classify(v.w, t, d3, s3);
        // merge + write previous group (lgkm wait lands here, behind classify)
        unsigned w0 = po0 + ps0;
        unsigned w1 = po1 + ps1 + (pd1 == pd0 ? ps0 : 0u);
        unsigned w2 = po2 + ps2 + (pd2 == pd0 ? ps0 : 0u) + (pd2 == pd1 ? ps1 : 0u);
        unsigned w3 = po3 + ps3 + (pd3 == pd0 ? ps0 : 0u) + (pd3 == pd1 ? ps1 : 0u)
                                + (pd3 == pd2 ? ps2 : 0u);
        cnt[pd0] = w0; cnt[pd1] = w1; cnt[pd2] = w2; cnt[pd3] = w3;
        // this group's reads AFTER previous writes (DS in-order per wave -> RAW safe)
        po0 = cnt[d0]; po1 = cnt[d1]; po2 = cnt[d2]; po3 = cnt[d3];
        pd0 = d0; pd1 = d1; pd2 = d2; pd3 = d3;
        ps0 = s0; ps1 = s1; ps2 = s2; ps3 = s3;
    };

    if (K > 0) {
        have_p = true;
        // peel iter 0: classify + initial reads (first "previous write" is a
        // benign re-write of slot t with +0 since ps*=0, po*=cnt[t])
        float4 A = x4[i0];
        process(A);

        if (K >= 3) {
            // distance-2 prefetch, unroll-2, named regs only (no scratch!)
            float4 B = x4[i0 + S];
            float4 C = x4[i0 + 2 * S];
            int k = 1;
            for (; k + 1 < K; k += 2) {
                float4 nb = x4[i0 + (k + 2 < K ? (k + 2) : 0) * S];
                process(B);                           // iter k
                float4 nc = x4[i0 + (k + 3 < K ? (k + 3) : 0) * S];
                process(C);                           // iter k+1
                B = nb; C = nc;
            }
            if (k < K) process(B);                    // leftover (K even)
        } else {
            for (int k = 1; k < K; ++k) {
                float4 B = x4[i0 + k * S];
                process(B);
            }
        }
    }
    // drain pipeline
    if (have_p) {
        unsigned w0 = po0 + ps0;
        unsigned w1 = po1 + ps1 + (pd1 == pd0 ? ps0 : 0u);
        unsigned w2 = po2 + ps2 + (pd2 == pd0 ? ps0 : 0u) + (pd2 == pd1 ? ps1 : 0u);
        unsigned w3 = po3 + ps3 + (pd3 == pd0 ? ps0 : 0u) + (pd3 == pd1 ? ps1 : 0u)
                                + (pd3 == pd2 ? ps2 : 0u);
        cnt[pd0] = w0; cnt[pd1] = w1; cnt[pd2] = w2; cnt[pd3] = w3;
    }

    // scalar remainder (n % 4)
    for (int j = (n4 << 2) + i0; j < n; j += S) {
        int d; unsigned s;
        classify(x[j], t, d, s);
        cnt[d] += s;
    }
    __syncthreads();

    // Epilogue: thread t -> quad q=t>>2, part p=t&3 sums 64 slices (rotated,
    // conflict-free: bank = ((j+t)&63)&31, distinct pairs across the wave).
    const int q = t >> 2;
    const int p = t & 3;
    unsigned accA = 0, accB = 0;   // packed u16 pairs: bytes{0,2} / bytes{1,3}
#pragma unroll 16
    for (int j = 0; j < 64; ++j) {
        unsigned u = cnt[(q << 8) + (p << 6) + ((j + t) & 63)];
        accA += u & 0x00FF00FFu;
        accB += (u >> 8) & 0x00FF00FFu;
    }
    // combine the 4 parts (consecutive lanes) via wave shuffles
    accA += __shfl_xor(accA, 1, 64);
    accA += __shfl_xor(accA, 2, 64);
    accB += __shfl_xor(accB, 1, 64);
    accB += __shfl_xor(accB, 2, 64);

    if (p == 0) {
        const unsigned b0 = accA & 0xFFFFu, b2 = accA >> 16;
        const unsigned b1 = accB & 0xFFFFu, b3 = accB >> 16;
        if (use_ws) {
            ((uint4*)(partial + (size_t)blockIdx.x * NBINS))[q] = make_uint4(b0, b1, b2, b3);
        } else {
            if (b0) atomicAdd(&out[4 * q + 0], (float)b0);
            if (b1) atomicAdd(&out[4 * q + 1], (float)b1);
            if (b2) atomicAdd(&out[4 * q + 2], (float)b2);
            if (b3) atomicAdd(&out[4 * q + 3], (float)b3);
        }
    }
}

// 256 blocks; block j sums a g-slice (coalesced 1 KB reads), <=256 atomics/bin total.
__global__ __launch_bounds__(NBINS) void reduce_kernel(const unsigned int* __restrict__ partial,
                                                       float* __restrict__ out,
                                                       int G, int slice) {
    const int bin = threadIdx.x;
    const int g0 = blockIdx.x * slice;
    const int g1 = (g0 + slice < G) ? (g0 + slice) : G;
    unsigned s = 0;
    for (int g = g0; g < g1; ++g)
        s += partial[(size_t)g * NBINS + bin];
    if (s) atomicAdd(&out[bin], (float)s);   // exact: integers < 2^24
}

__global__ void count_kernel(const void* __restrict__ bs_raw,
                             float* __restrict__ out) {
    const int as_int = *(const int*)bs_raw;
    float bs;
    if (as_int >= 1 && as_int < (1 << 20)) {
        bs = (float)as_int;
    } else {
        bs = *(const float*)bs_raw;
    }
    out[NBINS + threadIdx.x] = bs * out[0];
}

extern "C" void kernel_launch(void* const* d_in, const int* in_sizes, int n_in,
                              void* d_out, int out_size, void* d_ws, size_t ws_size,
                              hipStream_t stream) {
    const void* bs_ptr;
    const float* x;
    int n;
    if (n_in >= 2 && in_sizes[0] == 1) {
        bs_ptr = d_in[0];
        x = (const float*)d_in[1];
        n = in_sizes[1];
    } else {
        bs_ptr = d_in[1];
        x = (const float*)d_in[0];
        n = in_sizes[0];
    }

    float* out = (float*)d_out;                    // [256 hist | 256 count], float32
    unsigned int* partial = (unsigned int*)d_ws;   // [G][256] u32 partials

    // G: occupancy target, raised if needed so per-thread elements <= MAX_PER_THREAD
    long Gmin = ((long)n + (long)BLOCK * MAX_PER_THREAD - 1) / ((long)BLOCK * MAX_PER_THREAD);
    int G = (int)(Gmin > TARGET_G ? Gmin : TARGET_G);
    if (G < 1) G = 1;

    const size_t ws_need = (size_t)G * NBINS * sizeof(unsigned int);
    const int use_ws = (ws_size >= ws_need) ? 1 : 0;

    zero_out<<<2, 256, 0, stream>>>(out);
    hist_kernel<<<G, BLOCK, 0, stream>>>(x, partial, out, n, G, use_ws);
    if (use_ws) {
        const int slice = (G + NBINS - 1) / NBINS;
        reduce_kernel<<<NBINS, NBINS, 0, stream>>>(partial, out, G, slice);
    }
    count_kernel<<<1, NBINS, 0, stream>>>(bs_ptr, out);
}